// Round 3
// baseline (618.581 us; speedup 1.0000x reference)
//
#include <hip/hip_runtime.h>
#include <hip/hip_bf16.h>
#include <cstdint>
#include <cstddef>

#define NEG_ (-1e25f)
#define NBLK 512

typedef __bf16 bf16x8 __attribute__((ext_vector_type(8)));
typedef float  f32x4  __attribute__((ext_vector_type(4)));
typedef const __attribute__((address_space(1))) void* gas_t;
typedef __attribute__((address_space(3))) void* las_t;

__device__ __forceinline__ short f2bf(float f) {
  union { float f; unsigned u; } v; v.f = f;
  unsigned r = v.u + 0x7fffu + ((v.u >> 16) & 1u);  // RNE
  return (short)(r >> 16);
}

// ---- monotonic grid barrier: all NBLK blocks co-resident (launch_bounds(256,2)) ----
__device__ __forceinline__ void gsync(unsigned* cnt, unsigned target) {
  __threadfence();          // release our stores device-wide
  __syncthreads();          // drains vmem (compiler emits vmcnt(0))
  if (threadIdx.x == 0) {
    __hip_atomic_fetch_add(cnt, 1u, __ATOMIC_RELEASE, __HIP_MEMORY_SCOPE_AGENT);
    while (__hip_atomic_load(cnt, __ATOMIC_RELAXED, __HIP_MEMORY_SCOPE_AGENT) < target)
      __builtin_amdgcn_s_sleep(2);
  }
  __syncthreads();
  __threadfence();          // acquire: invalidate stale cache before next phase reads
}

// ---- pipelined 64x64 bt-GEMM tile: C[M,N] = A[M,K] @ B[N,K]^T ----
// PD=4 LDS ring, 3-ahead global_load_lds(16B), raw vmcnt/barrier pipeline.
// EPI 0: bf16 store. 1: bf16 + f32 gw2 side-store at col==512 (e0=gw2f out).
// 2: bf16, v += e0[row*1536+col] (Wo1 f32). 3: f32, v += e0[col] + e1[row]*e2[col].
template <int EPI>
__device__ void bt64_tile(
    const short* __restrict__ A, int lda, const short* __restrict__ B, int ldb,
    void* __restrict__ C, int ldc, int K, int m0, int n0,
    const float* e0, const float* e1, const float* e2, short* lds) {
  short* As = lds;               // 4 bufs * 2048 shorts
  short* Bs = lds + 4 * 2048;    // 4 bufs * 2048 shorts
  const int tid = threadIdx.x;
  const int wave = tid >> 6, lane = tid & 63;
  const int quad = lane >> 4, l16 = lane & 15;
  const int wm = (wave & 1) * 32, wn = (wave >> 1) * 32;
  const int srow = tid >> 2, scol = (tid & 3) * 8;
  const short* Ag = A + (long)(m0 + srow) * lda + scol;
  const short* Bg = B + (long)(n0 + srow) * ldb + scol;
  const int ldsoff = wave * 512;   // wave-uniform slab base (16 rows/wave)
  const int NT = K >> 5;
  auto issue = [&](int kt) {
    int buf = kt & 3; int ko = kt * 32;
    __builtin_amdgcn_global_load_lds((gas_t)(Ag + ko), (las_t)(As + buf * 2048 + ldsoff), 16, 0, 0);
    __builtin_amdgcn_global_load_lds((gas_t)(Bg + ko), (las_t)(Bs + buf * 2048 + ldsoff), 16, 0, 0);
  };
  f32x4 acc[2][2] = {};
  issue(0); issue(1); issue(2);
  for (int kt = 0; kt < NT; ++kt) {
    if (kt + 3 < NT) issue(kt + 3);
    int ahead = NT - 1 - kt; if (ahead > 3) ahead = 3;
    if (ahead == 3)      asm volatile("s_waitcnt vmcnt(6)" ::: "memory");
    else if (ahead == 2) asm volatile("s_waitcnt vmcnt(4)" ::: "memory");
    else if (ahead == 1) asm volatile("s_waitcnt vmcnt(2)" ::: "memory");
    else                 asm volatile("s_waitcnt vmcnt(0)" ::: "memory");
    asm volatile("s_barrier" ::: "memory");
    const short* as = As + (kt & 3) * 2048;
    const short* bs = Bs + (kt & 3) * 2048;
    bf16x8 a0 = *(const bf16x8*)&as[(wm + l16) * 32 + quad * 8];
    bf16x8 a1 = *(const bf16x8*)&as[(wm + 16 + l16) * 32 + quad * 8];
    bf16x8 b0 = *(const bf16x8*)&bs[(wn + l16) * 32 + quad * 8];
    bf16x8 b1 = *(const bf16x8*)&bs[(wn + 16 + l16) * 32 + quad * 8];
    acc[0][0] = __builtin_amdgcn_mfma_f32_16x16x32_bf16(a0, b0, acc[0][0], 0, 0, 0);
    acc[0][1] = __builtin_amdgcn_mfma_f32_16x16x32_bf16(a0, b1, acc[0][1], 0, 0, 0);
    acc[1][0] = __builtin_amdgcn_mfma_f32_16x16x32_bf16(a1, b0, acc[1][0], 0, 0, 0);
    acc[1][1] = __builtin_amdgcn_mfma_f32_16x16x32_bf16(a1, b1, acc[1][1], 0, 0, 0);
    asm volatile("s_barrier" ::: "memory");
  }
  #pragma unroll
  for (int i = 0; i < 2; ++i)
    #pragma unroll
    for (int j = 0; j < 2; ++j) {
      int col = n0 + wn + j * 16 + l16;
      #pragma unroll
      for (int r = 0; r < 4; ++r) {
        int row = m0 + wm + i * 16 + quad * 4 + r;
        float v = acc[i][j][r];
        if (EPI == 0) {
          ((short*)C)[(long)row * ldc + col] = f2bf(v);
        } else if (EPI == 1) {
          ((short*)C)[(long)row * ldc + col] = f2bf(v);
          if (col == 512) ((float*)e0)[row] = v;
        } else if (EPI == 2) {
          v += e0[(long)row * 1536 + col];
          ((short*)C)[(long)row * ldc + col] = f2bf(v);
        } else {
          v += e0[col] + e1[row] * e2[col];
          ((float*)C)[(long)row * ldc + col] = v;
        }
      }
    }
}

// ---- fused V/U gate 32x64 tile + Wa reduce -> atomicAdd into w ----
__device__ void vu_tile(int mi, int ni,
    const short* __restrict__ Xb, const short* __restrict__ Wvb,
    const short* __restrict__ Wub, const float* __restrict__ bv,
    const float* __restrict__ bu, const float* __restrict__ Wa,
    float* __restrict__ w, short* lds) {
  short* As = lds;               // 4 bufs * 1024 shorts
  short* Bs = lds + 4 * 1024;    // 4 bufs * 4096 shorts (rows 0:64 Wv, 64:128 Wu)
  const int tid = threadIdx.x;
  const int wave = tid >> 6, lane = tid & 63;
  const int quad = lane >> 4, l16 = lane & 15;
  const int wm = (wave & 1) * 16, wn = (wave >> 1) * 32;
  const int m0 = mi * 32, n0 = ni * 64;
  const int aseg = tid & 127;
  const int arow = aseg >> 2, acol = (aseg & 3) * 8;
  const int brow = tid >> 2, bcol = (tid & 3) * 8;
  const short* Agp = Xb + (long)(m0 + arow) * 1024 + acol;
  const short* Bvp = Wvb + (long)(n0 + brow) * 1024 + bcol;
  const short* Bup = Wub + (long)(n0 + brow) * 1024 + bcol;
  const int aoff = (wave & 1) * 512;
  const int bvoff = wave * 512;
  const int buoff = 2048 + wave * 512;
  auto issue = [&](int kt) {
    int buf = kt & 3; int ko = kt * 32;
    __builtin_amdgcn_global_load_lds((gas_t)(Agp + ko), (las_t)(As + buf * 1024 + aoff), 16, 0, 0);
    __builtin_amdgcn_global_load_lds((gas_t)(Bvp + ko), (las_t)(Bs + buf * 4096 + bvoff), 16, 0, 0);
    __builtin_amdgcn_global_load_lds((gas_t)(Bup + ko), (las_t)(Bs + buf * 4096 + buoff), 16, 0, 0);
  };
  f32x4 accv[2] = {}, accu[2] = {};
  issue(0); issue(1); issue(2);
  for (int kt = 0; kt < 32; ++kt) {
    if (kt + 3 < 32) issue(kt + 3);
    int ahead = 31 - kt; if (ahead > 3) ahead = 3;
    if (ahead == 3)      asm volatile("s_waitcnt vmcnt(9)" ::: "memory");
    else if (ahead == 2) asm volatile("s_waitcnt vmcnt(6)" ::: "memory");
    else if (ahead == 1) asm volatile("s_waitcnt vmcnt(3)" ::: "memory");
    else                 asm volatile("s_waitcnt vmcnt(0)" ::: "memory");
    asm volatile("s_barrier" ::: "memory");
    const short* as = As + (kt & 3) * 1024;
    const short* bs = Bs + (kt & 3) * 4096;
    bf16x8 af = *(const bf16x8*)&as[(wm + l16) * 32 + quad * 8];
    #pragma unroll
    for (int j = 0; j < 2; ++j) {
      bf16x8 bfv = *(const bf16x8*)&bs[(wn + j * 16 + l16) * 32 + quad * 8];
      bf16x8 bfu = *(const bf16x8*)&bs[(2048 + (wn + j * 16 + l16) * 32) + quad * 8];
      accv[j] = __builtin_amdgcn_mfma_f32_16x16x32_bf16(af, bfv, accv[j], 0, 0, 0);
      accu[j] = __builtin_amdgcn_mfma_f32_16x16x32_bf16(af, bfu, accu[j], 0, 0, 0);
    }
    asm volatile("s_barrier" ::: "memory");
  }
  float wsum[4] = {0.f, 0.f, 0.f, 0.f};
  #pragma unroll
  for (int j = 0; j < 2; ++j) {
    int col = n0 + wn + j * 16 + l16;
    float bvc = bv[col], buc = bu[col], wac = Wa[col];
    #pragma unroll
    for (int r = 0; r < 4; ++r) {
      float vv = tanhf(accv[j][r] + bvc);
      float uu = accu[j][r] + buc;
      wsum[r] += (vv / (1.0f + expf(-uu))) * wac;
    }
  }
  #pragma unroll
  for (int r = 0; r < 4; ++r) {
    float s = wsum[r];
    s += __shfl_down(s, 8, 16);
    s += __shfl_down(s, 4, 16);
    s += __shfl_down(s, 2, 16);
    s += __shfl_down(s, 1, 16);
    if (l16 == 0) atomicAdd(&w[m0 + wm + quad * 4 + r], s);
  }
}

// ---- masked softmax over K=16 + weighted pooling for one entity ----
__device__ void softmax_entity(int be, const float* __restrict__ ment,
    const int* __restrict__ ents, const int* __restrict__ msk,
    const float* __restrict__ w, const float* __restrict__ br,
    short* __restrict__ erb, float* __restrict__ cf,
    float* sm_a, int* sm_idx, float* sm_red) {
  const int b = be >> 7;  // E=128
  const int tid = threadIdx.x;
  __syncthreads();  // protect shared reuse across entities
  if (tid < 16) {
    int idx = ents[be * 16 + tid];
    sm_idx[tid] = idx;
    sm_a[tid] = msk[be * 16 + tid] ? w[(b << 8) + idx] : NEG_;
  }
  __syncthreads();
  if (tid == 0) {
    float mx = sm_a[0];
    #pragma unroll
    for (int k = 1; k < 16; ++k) mx = fmaxf(mx, sm_a[k]);
    float e[16], s = 0.f;
    #pragma unroll
    for (int k = 0; k < 16; ++k) { e[k] = expf(sm_a[k] - mx); s += e[k]; }
    float inv = 1.0f / s;
    #pragma unroll
    for (int k = 0; k < 16; ++k) sm_a[k] = e[k] * inv;
  }
  __syncthreads();
  const float* Xr = ment + ((long)b << 18);
  const int h0 = tid * 4;
  float ax = 0.f, ay = 0.f, az = 0.f, aw = 0.f;
  #pragma unroll
  for (int k = 0; k < 16; ++k) {
    float ak = sm_a[k];
    float4 xv = *(const float4*)&Xr[(long)sm_idx[k] * 1024 + h0];
    ax += ak * xv.x; ay += ak * xv.y; az += ak * xv.z; aw += ak * xv.w;
  }
  short* er = erb + (long)be * 1024 + h0;
  er[0] = f2bf(ax); er[1] = f2bf(ay); er[2] = f2bf(az); er[3] = f2bf(aw);
  float4 brv = *(const float4*)&br[h0];
  float c = ax * brv.x + ay * brv.y + az * brv.z + aw * brv.w;
  #pragma unroll
  for (int off = 32; off > 0; off >>= 1) c += __shfl_down(c, off);
  if ((tid & 63) == 0) sm_red[tid >> 6] = c;
  __syncthreads();
  if (tid == 0) cf[be] = sm_red[0] + sm_red[1] + sm_red[2] + sm_red[3];
}

// =======================  MEGA KERNEL  =======================
// P0 prep | P1 Gaug(72)+vu(256) | P2 T1(144)+softmax(256) | P3 Weff(256) | P4 out(256)
__global__ __launch_bounds__(256, 2) void mega(
    const float* __restrict__ ment, const int* __restrict__ ents,
    const int* __restrict__ msk, const float* __restrict__ rm,
    const float* __restrict__ Wv, const float* __restrict__ bv,
    const float* __restrict__ Wu, const float* __restrict__ bu,
    const float* __restrict__ Wa, const float* __restrict__ Wr,
    const float* __restrict__ br, const float* __restrict__ Wo,
    const float* __restrict__ bo, float* __restrict__ out,
    short* __restrict__ Xb, short* __restrict__ Wvb, short* __restrict__ Wub,
    short* __restrict__ Wrb, short* __restrict__ Wo2b, short* __restrict__ rmTaug,
    short* __restrict__ Gaugb, short* __restrict__ T1b, short* __restrict__ Weffb,
    short* __restrict__ erb, float* __restrict__ w, float* __restrict__ cf,
    float* __restrict__ gw2f, unsigned* cnt) {
  __shared__ alignas(16) short lds[20480];   // 40 KB: union of all tile layouts
  __shared__ float sm_a[16];
  __shared__ int   sm_idx[16];
  __shared__ float sm_red[4];
  const int blk = blockIdx.x, tid = threadIdx.x;

  // ---- P0: casts / transposes / augmentation / zero-init ----
  {
    const long S0 = 2097152, S1 = 262144, S2 = 262144, S3 = 524288, S4 = 524288,
               S5 = 524288, S6 = 1024, S7 = 64512, S8 = 2048;
    const long TOT = S0 + S1 + S2 + S3 + S4 + S5 + S6 + S7 + S8;
    for (long i = (long)blk * 256 + tid; i < TOT; i += (long)NBLK * 256) {
      long j = i;
      if (j < S0) { Xb[j] = f2bf(ment[j]); continue; } j -= S0;
      if (j < S1) { Wvb[j] = f2bf(Wv[j]); continue; } j -= S1;
      if (j < S2) { Wub[j] = f2bf(Wu[j]); continue; } j -= S2;
      if (j < S3) { Wrb[j] = f2bf(Wr[j]); continue; } j -= S3;      // [1024,512] native
      if (j < S4) { int h = (int)(j >> 9), m = (int)(j & 511);     // Wo2 split
                    Wo2b[j] = f2bf(Wo[(long)h * 1536 + 1024 + m]); continue; } j -= S4;
      if (j < S5) { int r = (int)(j >> 9), m = (int)(j & 511);     // rm -> rm^T
                    rmTaug[(long)m * 1024 + r] = f2bf(rm[j]); continue; } j -= S5;
      if (j < S6) { rmTaug[512 * 1024 + j] = (short)0x3F80; continue; } j -= S6;  // ones row
      if (j < S7) { rmTaug[513 * 1024 + j] = 0; continue; } j -= S7;              // zero pad
      w[j] = 0.f;
    }
  }
  gsync(cnt, 1u * NBLK);

  // ---- P1: Gaug = rmTaug @ rmTaug^T (rows 0:512 = G, row 512 = g)  +  vu gate ----
  if (blk < 72) {
    bt64_tile<0>(rmTaug, 1024, rmTaug, 1024, Gaugb, 512, 1024,
                 (blk / 8) * 64, (blk % 8) * 64, nullptr, nullptr, nullptr, lds);
  } else if (blk < 328) {
    int q = blk - 72;
    vu_tile(q >> 2, q & 3, Xb, Wvb, Wub, bv, bu, Wa, w, lds);
  }
  gsync(cnt, 2u * NBLK);

  // ---- P2: T1aug = Wo2 @ Gaug^T (col 512 -> gw2f)  +  softmax/pool ----
  if (blk < 144) {
    bt64_tile<1>(Wo2b, 512, Gaugb, 512, T1b, 576, 512,
                 (blk / 9) * 64, (blk % 9) * 64, (const float*)gw2f, nullptr, nullptr, lds);
  } else if (blk < 400) {
    int s4 = (blk - 144) * 4;
    for (int e = 0; e < 4; ++e)
      softmax_entity(s4 + e, ment, ents, msk, w, br, erb, cf, sm_a, sm_idx, sm_red);
  }
  gsync(cnt, 3u * NBLK);

  // ---- P3: Weff = Wo1 + T1 @ Wr^T ----
  if (blk < 256) {
    bt64_tile<2>(T1b, 576, Wrb, 512, Weffb, 1024, 512,
                 (blk >> 4) * 64, (blk & 15) * 64, Wo, nullptr, nullptr, lds);
  }
  gsync(cnt, 4u * NBLK);

  // ---- P4: out = er @ Weff^T + bo + c*gw2 ----
  if (blk < 256) {
    bt64_tile<3>(erb, 1024, Weffb, 1024, out, 1024, 1024,
                 (blk >> 4) * 64, (blk & 15) * 64, bo, cf, gw2f, lds);
  }
}

extern "C" void kernel_launch(void* const* d_in, const int* in_sizes, int n_in,
                              void* d_out, int out_size, void* d_ws, size_t ws_size,
                              hipStream_t stream) {
  const float* ment = (const float*)d_in[0];
  const int*   ents = (const int*)d_in[1];
  const int*   msk  = (const int*)d_in[2];
  const float* rm   = (const float*)d_in[3];
  const float* Wv   = (const float*)d_in[4];
  const float* bv   = (const float*)d_in[5];
  const float* Wu   = (const float*)d_in[6];
  const float* bu   = (const float*)d_in[7];
  const float* Wa   = (const float*)d_in[8];
  // d_in[9] = ba: drops out (softmax shift-invariance)
  const float* Wr   = (const float*)d_in[10];
  const float* br   = (const float*)d_in[11];
  const float* Wo   = (const float*)d_in[12];
  const float* bo   = (const float*)d_in[13];
  float* out = (float*)d_out;

  char* p = (char*)d_ws;
  auto alloc = [&](size_t bytes) {
    void* q = (void*)p; p += (bytes + 255) & ~(size_t)255; return q;
  };
  short* Xb     = (short*)alloc((size_t)2048 * 1024 * 2);
  short* Wvb    = (short*)alloc((size_t)256 * 1024 * 2);
  short* Wub    = (short*)alloc((size_t)256 * 1024 * 2);
  short* Wrb    = (short*)alloc((size_t)1024 * 512 * 2);
  short* Wo2b   = (short*)alloc((size_t)1024 * 512 * 2);
  short* rmTaug = (short*)alloc((size_t)576 * 1024 * 2);
  short* Gaugb  = (short*)alloc((size_t)576 * 512 * 2);
  short* T1b    = (short*)alloc((size_t)1024 * 576 * 2);
  short* Weffb  = (short*)alloc((size_t)1024 * 1024 * 2);
  short* erb    = (short*)alloc((size_t)1024 * 1024 * 2);
  float* w      = (float*)alloc((size_t)2048 * 4);
  float* cf     = (float*)alloc((size_t)1024 * 4);
  float* gw2f   = (float*)alloc((size_t)1024 * 4);
  unsigned* cnt = (unsigned*)alloc(256);

  hipMemsetAsync(cnt, 0, 4, stream);
  mega<<<NBLK, 256, 0, stream>>>(ment, ents, msk, rm, Wv, bv, Wu, bu, Wa, Wr, br,
                                 Wo, bo, out, Xb, Wvb, Wub, Wrb, Wo2b, rmTaug,
                                 Gaugb, T1b, Weffb, erb, w, cf, gw2f, cnt);
}

// Round 4
// 457.323 us; speedup vs baseline: 1.3526x; 1.3526x over previous
//
#include <hip/hip_runtime.h>
#include <hip/hip_bf16.h>
#include <cstdint>
#include <cstddef>

#define NEG_ (-1e25f)
#define NBLK 400

typedef __bf16 bf16x8 __attribute__((ext_vector_type(8)));
typedef float  f32x4  __attribute__((ext_vector_type(4)));
typedef const __attribute__((address_space(1))) void* gas_t;
typedef __attribute__((address_space(3))) void* las_t;

__device__ __forceinline__ short f2bf(float f) {
  union { float f; unsigned u; } v; v.f = f;
  unsigned r = v.u + 0x7fffu + ((v.u >> 16) & 1u);  // RNE
  return (short)(r >> 16);
}

// ---- two-level grid barrier: per-block arrival flags (64B slots) + single release ----
// No RMW contention: arrivals are stores to distinct lines; block 0 scans and
// publishes `rel`; spinners poll `rel` with ~0.4us backoff.
__device__ __forceinline__ void gsync(unsigned* flags, unsigned* rel, unsigned epoch) {
  __syncthreads();
  __threadfence();   // make this block's phase writes device-visible
  const int tid = threadIdx.x, blk = blockIdx.x;
  if (tid == 0)
    __hip_atomic_store(flags + blk * 16, epoch, __ATOMIC_RELEASE, __HIP_MEMORY_SCOPE_AGENT);
  if (blk == 0) {
    for (int i = tid; i < NBLK; i += 256)
      while (__hip_atomic_load(flags + i * 16, __ATOMIC_RELAXED, __HIP_MEMORY_SCOPE_AGENT) < epoch)
        __builtin_amdgcn_s_sleep(4);
    __syncthreads();
    if (tid == 0)
      __hip_atomic_store(rel, epoch, __ATOMIC_RELEASE, __HIP_MEMORY_SCOPE_AGENT);
  } else if (tid == 0) {
    while (__hip_atomic_load(rel, __ATOMIC_RELAXED, __HIP_MEMORY_SCOPE_AGENT) < epoch)
      __builtin_amdgcn_s_sleep(16);
  }
  __syncthreads();
  __threadfence();   // acquire: drop stale cached lines before next phase reads
}

// ---- pipelined 64x64 bt-GEMM tile: C[M,N] = A[M,K] @ B[N,K]^T ----
// PD=4 LDS ring, 3-ahead global_load_lds(16B), raw vmcnt/barrier pipeline.
// EPI 0: bf16 store. 1: bf16 + f32 gw2 side-store at col==512 (e0=gw2f out).
// 2: bf16, v += e0[row*1536+col] (Wo1 f32). 3: f32, v += e0[col] + e1[row]*e2[col].
template <int EPI>
__device__ void bt64_tile(
    const short* __restrict__ A, int lda, const short* __restrict__ B, int ldb,
    void* __restrict__ C, int ldc, int K, int m0, int n0,
    const float* e0, const float* e1, const float* e2, short* lds) {
  short* As = lds;               // 4 bufs * 2048 shorts
  short* Bs = lds + 4 * 2048;    // 4 bufs * 2048 shorts
  const int tid = threadIdx.x;
  const int wave = tid >> 6, lane = tid & 63;
  const int quad = lane >> 4, l16 = lane & 15;
  const int wm = (wave & 1) * 32, wn = (wave >> 1) * 32;
  const int srow = tid >> 2, scol = (tid & 3) * 8;
  const short* Ag = A + (long)(m0 + srow) * lda + scol;
  const short* Bg = B + (long)(n0 + srow) * ldb + scol;
  const int ldsoff = wave * 512;   // wave-uniform slab base (16 rows/wave)
  const int NT = K >> 5;
  auto issue = [&](int kt) {
    int buf = kt & 3; int ko = kt * 32;
    __builtin_amdgcn_global_load_lds((gas_t)(Ag + ko), (las_t)(As + buf * 2048 + ldsoff), 16, 0, 0);
    __builtin_amdgcn_global_load_lds((gas_t)(Bg + ko), (las_t)(Bs + buf * 2048 + ldsoff), 16, 0, 0);
  };
  f32x4 acc[2][2] = {};
  issue(0); issue(1); issue(2);
  for (int kt = 0; kt < NT; ++kt) {
    if (kt + 3 < NT) issue(kt + 3);
    int ahead = NT - 1 - kt; if (ahead > 3) ahead = 3;
    if (ahead == 3)      asm volatile("s_waitcnt vmcnt(6)" ::: "memory");
    else if (ahead == 2) asm volatile("s_waitcnt vmcnt(4)" ::: "memory");
    else if (ahead == 1) asm volatile("s_waitcnt vmcnt(2)" ::: "memory");
    else                 asm volatile("s_waitcnt vmcnt(0)" ::: "memory");
    asm volatile("s_barrier" ::: "memory");
    const short* as = As + (kt & 3) * 2048;
    const short* bs = Bs + (kt & 3) * 2048;
    bf16x8 a0 = *(const bf16x8*)&as[(wm + l16) * 32 + quad * 8];
    bf16x8 a1 = *(const bf16x8*)&as[(wm + 16 + l16) * 32 + quad * 8];
    bf16x8 b0 = *(const bf16x8*)&bs[(wn + l16) * 32 + quad * 8];
    bf16x8 b1 = *(const bf16x8*)&bs[(wn + 16 + l16) * 32 + quad * 8];
    acc[0][0] = __builtin_amdgcn_mfma_f32_16x16x32_bf16(a0, b0, acc[0][0], 0, 0, 0);
    acc[0][1] = __builtin_amdgcn_mfma_f32_16x16x32_bf16(a0, b1, acc[0][1], 0, 0, 0);
    acc[1][0] = __builtin_amdgcn_mfma_f32_16x16x32_bf16(a1, b0, acc[1][0], 0, 0, 0);
    acc[1][1] = __builtin_amdgcn_mfma_f32_16x16x32_bf16(a1, b1, acc[1][1], 0, 0, 0);
    asm volatile("s_barrier" ::: "memory");
  }
  #pragma unroll
  for (int i = 0; i < 2; ++i)
    #pragma unroll
    for (int j = 0; j < 2; ++j) {
      int col = n0 + wn + j * 16 + l16;
      #pragma unroll
      for (int r = 0; r < 4; ++r) {
        int row = m0 + wm + i * 16 + quad * 4 + r;
        float v = acc[i][j][r];
        if (EPI == 0) {
          ((short*)C)[(long)row * ldc + col] = f2bf(v);
        } else if (EPI == 1) {
          ((short*)C)[(long)row * ldc + col] = f2bf(v);
          if (col == 512) ((float*)e0)[row] = v;
        } else if (EPI == 2) {
          v += e0[(long)row * 1536 + col];
          ((short*)C)[(long)row * ldc + col] = f2bf(v);
        } else {
          v += e0[col] + e1[row] * e2[col];
          ((float*)C)[(long)row * ldc + col] = v;
        }
      }
    }
}

// ---- fused V/U gate 32x64 tile + Wa reduce -> atomicAdd into w ----
__device__ void vu_tile(int mi, int ni,
    const short* __restrict__ Xb, const short* __restrict__ Wvb,
    const short* __restrict__ Wub, const float* __restrict__ bv,
    const float* __restrict__ bu, const float* __restrict__ Wa,
    float* __restrict__ w, short* lds) {
  short* As = lds;               // 4 bufs * 1024 shorts
  short* Bs = lds + 4 * 1024;    // 4 bufs * 4096 shorts (rows 0:64 Wv, 64:128 Wu)
  const int tid = threadIdx.x;
  const int wave = tid >> 6, lane = tid & 63;
  const int quad = lane >> 4, l16 = lane & 15;
  const int wm = (wave & 1) * 16, wn = (wave >> 1) * 32;
  const int m0 = mi * 32, n0 = ni * 64;
  const int aseg = tid & 127;
  const int arow = aseg >> 2, acol = (aseg & 3) * 8;
  const int brow = tid >> 2, bcol = (tid & 3) * 8;
  const short* Agp = Xb + (long)(m0 + arow) * 1024 + acol;
  const short* Bvp = Wvb + (long)(n0 + brow) * 1024 + bcol;
  const short* Bup = Wub + (long)(n0 + brow) * 1024 + bcol;
  const int aoff = (wave & 1) * 512;
  const int bvoff = wave * 512;
  const int buoff = 2048 + wave * 512;
  auto issue = [&](int kt) {
    int buf = kt & 3; int ko = kt * 32;
    __builtin_amdgcn_global_load_lds((gas_t)(Agp + ko), (las_t)(As + buf * 1024 + aoff), 16, 0, 0);
    __builtin_amdgcn_global_load_lds((gas_t)(Bvp + ko), (las_t)(Bs + buf * 4096 + bvoff), 16, 0, 0);
    __builtin_amdgcn_global_load_lds((gas_t)(Bup + ko), (las_t)(Bs + buf * 4096 + buoff), 16, 0, 0);
  };
  f32x4 accv[2] = {}, accu[2] = {};
  issue(0); issue(1); issue(2);
  for (int kt = 0; kt < 32; ++kt) {
    if (kt + 3 < 32) issue(kt + 3);
    int ahead = 31 - kt; if (ahead > 3) ahead = 3;
    if (ahead == 3)      asm volatile("s_waitcnt vmcnt(9)" ::: "memory");
    else if (ahead == 2) asm volatile("s_waitcnt vmcnt(6)" ::: "memory");
    else if (ahead == 1) asm volatile("s_waitcnt vmcnt(3)" ::: "memory");
    else                 asm volatile("s_waitcnt vmcnt(0)" ::: "memory");
    asm volatile("s_barrier" ::: "memory");
    const short* as = As + (kt & 3) * 1024;
    const short* bs = Bs + (kt & 3) * 4096;
    bf16x8 af = *(const bf16x8*)&as[(wm + l16) * 32 + quad * 8];
    #pragma unroll
    for (int j = 0; j < 2; ++j) {
      bf16x8 bfv = *(const bf16x8*)&bs[(wn + j * 16 + l16) * 32 + quad * 8];
      bf16x8 bfu = *(const bf16x8*)&bs[(2048 + (wn + j * 16 + l16) * 32) + quad * 8];
      accv[j] = __builtin_amdgcn_mfma_f32_16x16x32_bf16(af, bfv, accv[j], 0, 0, 0);
      accu[j] = __builtin_amdgcn_mfma_f32_16x16x32_bf16(af, bfu, accu[j], 0, 0, 0);
    }
    asm volatile("s_barrier" ::: "memory");
  }
  float wsum[4] = {0.f, 0.f, 0.f, 0.f};
  #pragma unroll
  for (int j = 0; j < 2; ++j) {
    int col = n0 + wn + j * 16 + l16;
    float bvc = bv[col], buc = bu[col], wac = Wa[col];
    #pragma unroll
    for (int r = 0; r < 4; ++r) {
      float vv = tanhf(accv[j][r] + bvc);
      float uu = accu[j][r] + buc;
      wsum[r] += (vv / (1.0f + expf(-uu))) * wac;
    }
  }
  #pragma unroll
  for (int r = 0; r < 4; ++r) {
    float s = wsum[r];
    s += __shfl_down(s, 8, 16);
    s += __shfl_down(s, 4, 16);
    s += __shfl_down(s, 2, 16);
    s += __shfl_down(s, 1, 16);
    if (l16 == 0) atomicAdd(&w[m0 + wm + quad * 4 + r], s);
  }
}

// ---- masked softmax over K=16 + weighted pooling for one entity ----
__device__ void softmax_entity(int be, const float* __restrict__ ment,
    const int* __restrict__ ents, const int* __restrict__ msk,
    const float* __restrict__ w, const float* __restrict__ br,
    short* __restrict__ erb, float* __restrict__ cf,
    float* sm_a, int* sm_idx, float* sm_red) {
  const int b = be >> 7;  // E=128
  const int tid = threadIdx.x;
  __syncthreads();  // protect shared reuse across entities
  if (tid < 16) {
    int idx = ents[be * 16 + tid];
    sm_idx[tid] = idx;
    sm_a[tid] = msk[be * 16 + tid] ? w[(b << 8) + idx] : NEG_;
  }
  __syncthreads();
  if (tid == 0) {
    float mx = sm_a[0];
    #pragma unroll
    for (int k = 1; k < 16; ++k) mx = fmaxf(mx, sm_a[k]);
    float e[16], s = 0.f;
    #pragma unroll
    for (int k = 0; k < 16; ++k) { e[k] = expf(sm_a[k] - mx); s += e[k]; }
    float inv = 1.0f / s;
    #pragma unroll
    for (int k = 0; k < 16; ++k) sm_a[k] = e[k] * inv;
  }
  __syncthreads();
  const float* Xr = ment + ((long)b << 18);
  const int h0 = tid * 4;
  float ax = 0.f, ay = 0.f, az = 0.f, aw = 0.f;
  #pragma unroll
  for (int k = 0; k < 16; ++k) {
    float ak = sm_a[k];
    float4 xv = *(const float4*)&Xr[(long)sm_idx[k] * 1024 + h0];
    ax += ak * xv.x; ay += ak * xv.y; az += ak * xv.z; aw += ak * xv.w;
  }
  short* er = erb + (long)be * 1024 + h0;
  er[0] = f2bf(ax); er[1] = f2bf(ay); er[2] = f2bf(az); er[3] = f2bf(aw);
  float4 brv = *(const float4*)&br[h0];
  float c = ax * brv.x + ay * brv.y + az * brv.z + aw * brv.w;
  #pragma unroll
  for (int off = 32; off > 0; off >>= 1) c += __shfl_down(c, off);
  if ((tid & 63) == 0) sm_red[tid >> 6] = c;
  __syncthreads();
  if (tid == 0) cf[be] = sm_red[0] + sm_red[1] + sm_red[2] + sm_red[3];
}

// =======================  MEGA KERNEL  =======================
// P0 prep | P1 Gaug(72)+vu(256) | P2 T1(144)+softmax(256) | P3 Weff(256) | P4 out(256)
__global__ __launch_bounds__(256, 2) void mega(
    const float* __restrict__ ment, const int* __restrict__ ents,
    const int* __restrict__ msk, const float* __restrict__ rm,
    const float* __restrict__ Wv, const float* __restrict__ bv,
    const float* __restrict__ Wu, const float* __restrict__ bu,
    const float* __restrict__ Wa, const float* __restrict__ Wr,
    const float* __restrict__ br, const float* __restrict__ Wo,
    const float* __restrict__ bo, float* __restrict__ out,
    short* __restrict__ Xb, short* __restrict__ Wvb, short* __restrict__ Wub,
    short* __restrict__ Wrb, short* __restrict__ Wo2b, short* __restrict__ rmTaug,
    short* __restrict__ Gaugb, short* __restrict__ T1b, short* __restrict__ Weffb,
    short* __restrict__ erb, float* __restrict__ w, float* __restrict__ cf,
    float* __restrict__ gw2f, unsigned* flags, unsigned* rel) {
  __shared__ alignas(16) short lds[20480];   // 40 KB: union of all tile layouts
  __shared__ float sm_a[16];
  __shared__ int   sm_idx[16];
  __shared__ float sm_red[4];
  const int blk = blockIdx.x, tid = threadIdx.x;

  // ---- P0: casts / transposes / augmentation / zero-init ----
  {
    const long S0 = 2097152, S1 = 262144, S2 = 262144, S3 = 524288, S4 = 524288,
               S5 = 524288, S6 = 1024, S7 = 64512, S8 = 2048;
    const long TOT = S0 + S1 + S2 + S3 + S4 + S5 + S6 + S7 + S8;
    for (long i = (long)blk * 256 + tid; i < TOT; i += (long)NBLK * 256) {
      long j = i;
      if (j < S0) { Xb[j] = f2bf(ment[j]); continue; } j -= S0;
      if (j < S1) { Wvb[j] = f2bf(Wv[j]); continue; } j -= S1;
      if (j < S2) { Wub[j] = f2bf(Wu[j]); continue; } j -= S2;
      if (j < S3) { Wrb[j] = f2bf(Wr[j]); continue; } j -= S3;      // [1024,512] native
      if (j < S4) { int h = (int)(j >> 9), m = (int)(j & 511);     // Wo2 split
                    Wo2b[j] = f2bf(Wo[(long)h * 1536 + 1024 + m]); continue; } j -= S4;
      if (j < S5) { int r = (int)(j >> 9), m = (int)(j & 511);     // rm -> rm^T
                    rmTaug[(long)m * 1024 + r] = f2bf(rm[j]); continue; } j -= S5;
      if (j < S6) { rmTaug[512 * 1024 + j] = (short)0x3F80; continue; } j -= S6;  // ones row
      if (j < S7) { rmTaug[513 * 1024 + j] = 0; continue; } j -= S7;              // zero pad
      w[j] = 0.f;
    }
  }
  gsync(flags, rel, 1u);

  // ---- P1: Gaug = rmTaug @ rmTaug^T (rows 0:512 = G, row 512 = g)  +  vu gate ----
  if (blk < 72) {
    bt64_tile<0>(rmTaug, 1024, rmTaug, 1024, Gaugb, 512, 1024,
                 (blk / 8) * 64, (blk % 8) * 64, nullptr, nullptr, nullptr, lds);
  } else if (blk < 328) {
    int q = blk - 72;
    vu_tile(q >> 2, q & 3, Xb, Wvb, Wub, bv, bu, Wa, w, lds);
  }
  gsync(flags, rel, 2u);

  // ---- P2: T1aug = Wo2 @ Gaug^T (col 512 -> gw2f)  +  softmax/pool ----
  if (blk < 144) {
    bt64_tile<1>(Wo2b, 512, Gaugb, 512, T1b, 576, 512,
                 (blk / 9) * 64, (blk % 9) * 64, (const float*)gw2f, nullptr, nullptr, lds);
  } else if (blk < 400) {
    int s4 = (blk - 144) * 4;
    for (int e = 0; e < 4; ++e)
      softmax_entity(s4 + e, ment, ents, msk, w, br, erb, cf, sm_a, sm_idx, sm_red);
  }
  gsync(flags, rel, 3u);

  // ---- P3: Weff = Wo1 + T1 @ Wr^T ----
  if (blk < 256) {
    bt64_tile<2>(T1b, 576, Wrb, 512, Weffb, 1024, 512,
                 (blk >> 4) * 64, (blk & 15) * 64, Wo, nullptr, nullptr, lds);
  }
  gsync(flags, rel, 4u);

  // ---- P4: out = er @ Weff^T + bo + c*gw2 ----
  if (blk < 256) {
    bt64_tile<3>(erb, 1024, Weffb, 1024, out, 1024, 1024,
                 (blk >> 4) * 64, (blk & 15) * 64, bo, cf, gw2f, lds);
  }
}

extern "C" void kernel_launch(void* const* d_in, const int* in_sizes, int n_in,
                              void* d_out, int out_size, void* d_ws, size_t ws_size,
                              hipStream_t stream) {
  const float* ment = (const float*)d_in[0];
  const int*   ents = (const int*)d_in[1];
  const int*   msk  = (const int*)d_in[2];
  const float* rm   = (const float*)d_in[3];
  const float* Wv   = (const float*)d_in[4];
  const float* bv   = (const float*)d_in[5];
  const float* Wu   = (const float*)d_in[6];
  const float* bu   = (const float*)d_in[7];
  const float* Wa   = (const float*)d_in[8];
  // d_in[9] = ba: drops out (softmax shift-invariance)
  const float* Wr   = (const float*)d_in[10];
  const float* br   = (const float*)d_in[11];
  const float* Wo   = (const float*)d_in[12];
  const float* bo   = (const float*)d_in[13];
  float* out = (float*)d_out;

  char* p = (char*)d_ws;
  auto alloc = [&](size_t bytes) {
    void* q = (void*)p; p += (bytes + 255) & ~(size_t)255; return q;
  };
  short* Xb     = (short*)alloc((size_t)2048 * 1024 * 2);
  short* Wvb    = (short*)alloc((size_t)256 * 1024 * 2);
  short* Wub    = (short*)alloc((size_t)256 * 1024 * 2);
  short* Wrb    = (short*)alloc((size_t)1024 * 512 * 2);
  short* Wo2b   = (short*)alloc((size_t)1024 * 512 * 2);
  short* rmTaug = (short*)alloc((size_t)576 * 1024 * 2);
  short* Gaugb  = (short*)alloc((size_t)576 * 512 * 2);
  short* T1b    = (short*)alloc((size_t)1024 * 576 * 2);
  short* Weffb  = (short*)alloc((size_t)1024 * 1024 * 2);
  short* erb    = (short*)alloc((size_t)1024 * 1024 * 2);
  float* w      = (float*)alloc((size_t)2048 * 4);
  float* cf     = (float*)alloc((size_t)1024 * 4);
  float* gw2f   = (float*)alloc((size_t)1024 * 4);
  unsigned* sync = (unsigned*)alloc(32768);   // flags: NBLK*64B slots, then rel
  unsigned* flags = sync;
  unsigned* rel   = sync + NBLK * 16;

  hipMemsetAsync(sync, 0, 32768, stream);
  mega<<<NBLK, 256, 0, stream>>>(ment, ents, msk, rm, Wv, bv, Wu, bu, Wa, Wr, br,
                                 Wo, bo, out, Xb, Wvb, Wub, Wrb, Wo2b, rmTaug,
                                 Gaugb, T1b, Weffb, erb, w, cf, gw2f, flags, rel);
}

// Round 5
// 192.871 us; speedup vs baseline: 3.2072x; 2.3711x over previous
//
#include <hip/hip_runtime.h>
#include <cstdint>
#include <cstddef>

#define NEG_ (-1e25f)

typedef __bf16 bf16x8 __attribute__((ext_vector_type(8)));
typedef float  f32x4  __attribute__((ext_vector_type(4)));

#define MFMA16 __builtin_amdgcn_mfma_f32_16x16x32_bf16

// load 8 f32 with compile-time stride SK (float4 pairs when contiguous)
template <long SK>
__device__ __forceinline__ void load8(const float* __restrict__ p, float* d) {
  if constexpr (SK == 1) {
    float4 v0 = *(const float4*)p;
    float4 v1 = *(const float4*)(p + 4);
    d[0] = v0.x; d[1] = v0.y; d[2] = v0.z; d[3] = v0.w;
    d[4] = v1.x; d[5] = v1.y; d[6] = v1.z; d[7] = v1.w;
  } else {
    #pragma unroll
    for (int j = 0; j < 8; ++j) d[j] = p[j * SK];
  }
}

__device__ __forceinline__ bf16x8 cvt8(const float* s) {
  bf16x8 r;
  #pragma unroll
  for (int j = 0; j < 8; ++j) r[j] = (__bf16)s[j];  // fptrunc = RNE
  return r;
}

// ---- convert-on-load 64x64 GEMM tile, direct-fragment, no LDS, 2-stage pipeline ----
// C[m,n] = sum_k A[m][k] * B[n][k];  A elem addr = A + m*A_SM + k*A_SK (f32), same for B.
// GA: A has virtual ones-row at m==512, zeros beyond (Gaug augmentation).
// EPI 0: plain f32 store. 1: store iff col<513 (T1, ldc=520).
// 2: v += e0[row*1536+col] (Weff += Wo1). 3: v += e0[col] + e1[row]*e2[col*520+512] (out).
template <int NT, long A_SM, long A_SK, long B_SN, long B_SK, bool GA, int EPI>
__device__ void cgemm(const float* __restrict__ A, const float* __restrict__ B,
                      float* __restrict__ C, int ldc, int m0, int n0,
                      const float* __restrict__ e0, const float* __restrict__ e1,
                      const float* __restrict__ e2) {
  const int tid = threadIdx.x;
  const int wave = tid >> 6, lane = tid & 63;
  const int quad = lane >> 4, l16 = lane & 15;
  const int wm = (wave & 1) * 32, wn = (wave >> 1) * 32;
  int ma[2], nb[2];
  ma[0] = m0 + wm + l16; ma[1] = ma[0] + 16;
  nb[0] = n0 + wn + l16; nb[1] = nb[0] + 16;
  const float* ap[2]; const float* bp[2]; bool aok[2]; float afix[2];
  #pragma unroll
  for (int i = 0; i < 2; ++i) {
    ap[i] = A + (long)ma[i] * A_SM;
    bp[i] = B + (long)nb[i] * B_SN;
    if constexpr (GA) { aok[i] = ma[i] < 512; afix[i] = (ma[i] == 512) ? 1.f : 0.f; }
    else              { aok[i] = true; afix[i] = 0.f; }
  }
  const int kq = quad * 8;
  float s0[32], s1[32];
  auto ld = [&](int kt, float* st) {
    long k = (long)kt * 32 + kq;
    #pragma unroll
    for (int i = 0; i < 2; ++i) {
      if constexpr (GA) {
        if (aok[i]) load8<A_SK>(ap[i] + k * A_SK, st + i * 8);
        else {
          #pragma unroll
          for (int j = 0; j < 8; ++j) st[i * 8 + j] = afix[i];
        }
      } else {
        load8<A_SK>(ap[i] + k * A_SK, st + i * 8);
      }
    }
    #pragma unroll
    for (int i = 0; i < 2; ++i) load8<B_SK>(bp[i] + k * B_SK, st + 16 + i * 8);
  };
  f32x4 acc[2][2] = {};
  auto step = [&](float* st) {
    bf16x8 a0 = cvt8(st), a1 = cvt8(st + 8);
    bf16x8 b0 = cvt8(st + 16), b1 = cvt8(st + 24);
    acc[0][0] = MFMA16(a0, b0, acc[0][0], 0, 0, 0);
    acc[0][1] = MFMA16(a0, b1, acc[0][1], 0, 0, 0);
    acc[1][0] = MFMA16(a1, b0, acc[1][0], 0, 0, 0);
    acc[1][1] = MFMA16(a1, b1, acc[1][1], 0, 0, 0);
  };
  ld(0, s0); ld(1, s1);
  #pragma unroll 1
  for (int kt = 0; kt < NT; kt += 2) {
    step(s0); if (kt + 2 < NT) ld(kt + 2, s0);
    step(s1); if (kt + 3 < NT) ld(kt + 3, s1);
  }
  #pragma unroll
  for (int i = 0; i < 2; ++i)
    #pragma unroll
    for (int j = 0; j < 2; ++j) {
      int col = n0 + wn + j * 16 + l16;
      #pragma unroll
      for (int r = 0; r < 4; ++r) {
        int row = m0 + wm + i * 16 + quad * 4 + r;
        float v = acc[i][j][r];
        if constexpr (EPI == 0) {
          C[(long)row * ldc + col] = v;
        } else if constexpr (EPI == 1) {
          if (col < 513) C[(long)row * ldc + col] = v;
        } else if constexpr (EPI == 2) {
          C[(long)row * ldc + col] = v + e0[(long)row * 1536 + col];
        } else {
          C[(long)row * ldc + col] = v + e0[col] + e1[row] * e2[(long)col * 520 + 512];
        }
      }
    }
}

// ---- vu gate tile 32(M)x64(N): dual-B (Wv,Wu), gate+Wa reduce -> wpart[ni][2048] ----
__device__ void vu_tile(int mi, int ni, const float* __restrict__ X,
                        const float* __restrict__ Wv, const float* __restrict__ Wu,
                        const float* __restrict__ bv, const float* __restrict__ bu,
                        const float* __restrict__ Wa, float* __restrict__ wpart,
                        float* red) {
  const int tid = threadIdx.x;
  const int wave = tid >> 6, lane = tid & 63;
  const int quad = lane >> 4, l16 = lane & 15;
  const int wm = (wave & 1) * 16, wn = (wave >> 1) * 32;
  const int m0 = mi * 32, n0 = ni * 64;
  const int m = m0 + wm + l16;
  int nn[2] = { n0 + wn + l16, n0 + wn + 16 + l16 };
  const float* apx = X + (long)m * 1024;
  const float* bvp[2] = { Wv + (long)nn[0] * 1024, Wv + (long)nn[1] * 1024 };
  const float* bup[2] = { Wu + (long)nn[0] * 1024, Wu + (long)nn[1] * 1024 };
  const int kq = quad * 8;
  float s0[40], s1[40];
  auto ld = [&](int kt, float* st) {
    long k = (long)kt * 32 + kq;
    load8<1>(apx + k, st);
    load8<1>(bvp[0] + k, st + 8);
    load8<1>(bvp[1] + k, st + 16);
    load8<1>(bup[0] + k, st + 24);
    load8<1>(bup[1] + k, st + 32);
  };
  f32x4 accv[2] = {}, accu[2] = {};
  auto step = [&](float* st) {
    bf16x8 af = cvt8(st);
    bf16x8 v0 = cvt8(st + 8), v1 = cvt8(st + 16);
    bf16x8 u0 = cvt8(st + 24), u1 = cvt8(st + 32);
    accv[0] = MFMA16(af, v0, accv[0], 0, 0, 0);
    accv[1] = MFMA16(af, v1, accv[1], 0, 0, 0);
    accu[0] = MFMA16(af, u0, accu[0], 0, 0, 0);
    accu[1] = MFMA16(af, u1, accu[1], 0, 0, 0);
  };
  ld(0, s0); ld(1, s1);
  #pragma unroll 1
  for (int kt = 0; kt < 32; kt += 2) {
    step(s0); if (kt + 2 < 32) ld(kt + 2, s0);
    step(s1); if (kt + 3 < 32) ld(kt + 3, s1);
  }
  float wsum[4] = {0.f, 0.f, 0.f, 0.f};
  #pragma unroll
  for (int j = 0; j < 2; ++j) {
    int col = n0 + wn + j * 16 + l16;
    float bvc = bv[col], buc = bu[col], wac = Wa[col];
    #pragma unroll
    for (int r = 0; r < 4; ++r) {
      float vv = tanhf(accv[j][r] + bvc);
      float uu = accu[j][r] + buc;
      wsum[r] += (vv / (1.0f + expf(-uu))) * wac;
    }
  }
  #pragma unroll
  for (int r = 0; r < 4; ++r) {
    float s = wsum[r];
    s += __shfl_down(s, 8, 16);
    s += __shfl_down(s, 4, 16);
    s += __shfl_down(s, 2, 16);
    s += __shfl_down(s, 1, 16);
    if (l16 == 0) red[(wave >> 1) * 32 + wm + quad * 4 + r] = s;  // two n-half waves
  }
  __syncthreads();
  if (tid < 32) wpart[ni * 2048 + m0 + tid] = red[tid] + red[32 + tid];
}

// ---- masked softmax over K=16 + pooling for one entity -> er (f32), cf ----
__device__ void softmax_entity(int be, const float* __restrict__ ment,
    const int* __restrict__ ents, const int* __restrict__ msk,
    const float* __restrict__ wpart, const float* __restrict__ br,
    float* __restrict__ erb, float* __restrict__ cf,
    float* sm_a, int* sm_idx, float* sm_red) {
  const int b = be >> 7;  // E=128
  const int tid = threadIdx.x;
  __syncthreads();  // protect shared reuse across entities
  if (tid < 16) {
    int idx = ents[be * 16 + tid];
    sm_idx[tid] = idx;
    int j = (b << 8) + idx;
    float lw = wpart[j] + wpart[2048 + j] + wpart[4096 + j] + wpart[6144 + j];
    sm_a[tid] = msk[be * 16 + tid] ? lw : NEG_;
  }
  __syncthreads();
  if (tid == 0) {
    float mx = sm_a[0];
    #pragma unroll
    for (int k = 1; k < 16; ++k) mx = fmaxf(mx, sm_a[k]);
    float e[16], s = 0.f;
    #pragma unroll
    for (int k = 0; k < 16; ++k) { e[k] = expf(sm_a[k] - mx); s += e[k]; }
    float inv = 1.0f / s;
    #pragma unroll
    for (int k = 0; k < 16; ++k) sm_a[k] = e[k] * inv;
  }
  __syncthreads();
  const float* Xr = ment + ((long)b << 18);
  const int h0 = tid * 4;
  float ax = 0.f, ay = 0.f, az = 0.f, aw = 0.f;
  #pragma unroll
  for (int k = 0; k < 16; ++k) {
    float ak = sm_a[k];
    float4 xv = *(const float4*)&Xr[(long)sm_idx[k] * 1024 + h0];
    ax += ak * xv.x; ay += ak * xv.y; az += ak * xv.z; aw += ak * xv.w;
  }
  float4 o; o.x = ax; o.y = ay; o.z = az; o.w = aw;
  *(float4*)&erb[(long)be * 1024 + h0] = o;
  float4 brv = *(const float4*)&br[h0];
  float c = ax * brv.x + ay * brv.y + az * brv.z + aw * brv.w;
  #pragma unroll
  for (int off = 32; off > 0; off >>= 1) c += __shfl_down(c, off);
  if ((tid & 63) == 0) sm_red[tid >> 6] = c;
  __syncthreads();
  if (tid == 0) cf[be] = sm_red[0] + sm_red[1] + sm_red[2] + sm_red[3];
}

// ================= kernels =================
// L1: Gaug = [rm^T rm ; g^T ; 0] (72 blocks)  ||  vu gate -> wpart (256 blocks)
__global__ __launch_bounds__(256) void k1(
    const float* __restrict__ rm, const float* __restrict__ ment,
    const float* __restrict__ Wv, const float* __restrict__ Wu,
    const float* __restrict__ bv, const float* __restrict__ bu,
    const float* __restrict__ Wa, float* __restrict__ Gaug,
    float* __restrict__ wpart) {
  __shared__ float red[64];
  const int blk = blockIdx.x;
  if (blk < 72) {
    // A[i][k]=rm[k*512+i] (i<512; i==512 -> 1; else 0), B[n][k]=rm[k*512+n]
    cgemm<32, 1, 512, 1, 512, true, 0>(rm, rm, Gaug, 512,
                                       (blk / 8) * 64, (blk % 8) * 64,
                                       nullptr, nullptr, nullptr);
  } else {
    int q = blk - 72;
    vu_tile(q >> 2, q & 3, ment, Wv, Wu, bv, bu, Wa, wpart, red);
  }
}

// L2: T1 = Wo2 @ Gaug^T [1024 x 513] ldc=520 (144 blocks)  ||  softmax (256 blocks x 4)
__global__ __launch_bounds__(256) void k2(
    const float* __restrict__ Wo, const float* __restrict__ Gaug,
    const float* __restrict__ ment, const int* __restrict__ ents,
    const int* __restrict__ msk, const float* __restrict__ wpart,
    const float* __restrict__ br, float* __restrict__ T1,
    float* __restrict__ erb, float* __restrict__ cf) {
  __shared__ float sm_a[16];
  __shared__ int   sm_idx[16];
  __shared__ float sm_red[4];
  const int blk = blockIdx.x;
  if (blk < 144) {
    // A=Wo2: addr Wo + h*1536 + 1024 + m ; B=Gaug[i*512+m]
    cgemm<16, 1536, 1, 512, 1, false, 1>(Wo + 1024, Gaug, T1, 520,
                                         (blk / 9) * 64, (blk % 9) * 64,
                                         nullptr, nullptr, nullptr);
  } else {
    int s4 = (blk - 144) * 4;
    for (int e = 0; e < 4; ++e)
      softmax_entity(s4 + e, ment, ents, msk, wpart, br, erb, cf,
                     sm_a, sm_idx, sm_red);
  }
}

// L3: Weff = Wo1 + T1 @ Wr^T [1024 x 1024] (256 blocks)
__global__ __launch_bounds__(256) void k3(
    const float* __restrict__ T1, const float* __restrict__ Wr,
    const float* __restrict__ Wo, float* __restrict__ Weff) {
  const int blk = blockIdx.x;
  cgemm<16, 520, 1, 512, 1, false, 2>(T1, Wr, Weff, 1024,
                                      (blk >> 4) * 64, (blk & 15) * 64,
                                      Wo, nullptr, nullptr);
}

// L4: out = er @ Weff^T + bo + cf*gw2 [1024 x 1024] (256 blocks)
__global__ __launch_bounds__(256) void k4(
    const float* __restrict__ erb, const float* __restrict__ Weff,
    const float* __restrict__ bo, const float* __restrict__ cf,
    const float* __restrict__ T1, float* __restrict__ out) {
  const int blk = blockIdx.x;
  cgemm<32, 1024, 1, 1024, 1, false, 3>(erb, Weff, out, 1024,
                                        (blk >> 4) * 64, (blk & 15) * 64,
                                        bo, cf, T1);
}

extern "C" void kernel_launch(void* const* d_in, const int* in_sizes, int n_in,
                              void* d_out, int out_size, void* d_ws, size_t ws_size,
                              hipStream_t stream) {
  const float* ment = (const float*)d_in[0];
  const int*   ents = (const int*)d_in[1];
  const int*   msk  = (const int*)d_in[2];
  const float* rm   = (const float*)d_in[3];
  const float* Wv   = (const float*)d_in[4];
  const float* bv   = (const float*)d_in[5];
  const float* Wu   = (const float*)d_in[6];
  const float* bu   = (const float*)d_in[7];
  const float* Wa   = (const float*)d_in[8];
  // d_in[9] = ba: drops out (softmax shift-invariance)
  const float* Wr   = (const float*)d_in[10];
  const float* br   = (const float*)d_in[11];
  const float* Wo   = (const float*)d_in[12];
  const float* bo   = (const float*)d_in[13];
  float* out = (float*)d_out;

  char* p = (char*)d_ws;
  auto alloc = [&](size_t bytes) {
    void* q = (void*)p; p += (bytes + 255) & ~(size_t)255; return q;
  };
  float* Gaug  = (float*)alloc((size_t)576 * 512 * 4);   // rows 0:512=G, 512=g, rest 0
  float* wpart = (float*)alloc((size_t)4 * 2048 * 4);    // per-n-block gate partials
  float* T1    = (float*)alloc((size_t)1024 * 520 * 4);  // cols 0:512=T1, col 512=gw2
  float* erb   = (float*)alloc((size_t)1024 * 1024 * 4); // entity reprs (f32)
  float* cf    = (float*)alloc((size_t)1024 * 4);        // er . br
  float* Weff  = (float*)alloc((size_t)1024 * 1024 * 4);

  k1<<<328, 256, 0, stream>>>(rm, ment, Wv, Wu, bv, bu, Wa, Gaug, wpart);
  k2<<<400, 256, 0, stream>>>(Wo, Gaug, ment, ents, msk, wpart, br, T1, erb, cf);
  k3<<<256, 256, 0, stream>>>(T1, Wr, Wo, Weff);
  k4<<<256, 256, 0, stream>>>(erb, Weff, bo, cf, T1, out);
}

// Round 6
// 141.797 us; speedup vs baseline: 4.3625x; 1.3602x over previous
//
#include <hip/hip_runtime.h>
#include <cstdint>
#include <cstddef>

#define NEG_ (-1e25f)

typedef __bf16 bf16x8 __attribute__((ext_vector_type(8)));
typedef float  f32x4  __attribute__((ext_vector_type(4)));
typedef short  s16x8  __attribute__((ext_vector_type(8)));
typedef const __attribute__((address_space(1))) void* gas_t;
typedef __attribute__((address_space(3))) void* las_t;

#define MFMA16 __builtin_amdgcn_mfma_f32_16x16x32_bf16

__device__ __forceinline__ short f2bf(float f) {
  union { float f; unsigned u; } v; v.f = f;
  unsigned r = v.u + 0x7fffu + ((v.u >> 16) & 1u);  // RNE
  return (short)(r >> 16);
}

__device__ __forceinline__ s16x8 cvt8(const float* s) {
  bf16x8 r;
  #pragma unroll
  for (int j = 0; j < 8; ++j) r[j] = (__bf16)s[j];  // fptrunc = RNE
  union { bf16x8 b; s16x8 s; } u; u.b = r; return u.s;
}

// ---- f32-input 64x64 GEMM: C_bf16[M,N] = A_f32[M,K] @ B_f32[N,K]^T ----
// Coalesced float4 staging -> reg (1-ahead prefetch) -> cvt bf16 -> ds_write_b128,
// single LDS buffer, 2 barriers/iter, b128 frag reads, 4 MFMA/iter/wave.
template <int NT>
__device__ void fgemm64(const float* __restrict__ A, long lda,
                        const float* __restrict__ B, long ldb,
                        short* __restrict__ C, int ldc, int m0, int n0,
                        short* lds) {
  const int tid = threadIdx.x, wave = tid >> 6, lane = tid & 63;
  const int quad = lane >> 4, l16 = lane & 15;
  const int wm = (wave & 1) * 32, wn = (wave >> 1) * 32;
  const int srow = tid >> 2, scol = (tid & 3) * 8;
  const float* Ag = A + (long)(m0 + srow) * lda + scol;
  const float* Bg = B + (long)(n0 + srow) * ldb + scol;
  short* As = lds; short* Bs = lds + 2048;
  float ra[8], rb[8];
  auto gload = [&](int kt) {
    long k = (long)kt * 32;
    *(float4*)(ra)     = *(const float4*)(Ag + k);
    *(float4*)(ra + 4) = *(const float4*)(Ag + k + 4);
    *(float4*)(rb)     = *(const float4*)(Bg + k);
    *(float4*)(rb + 4) = *(const float4*)(Bg + k + 4);
  };
  f32x4 acc[2][2] = {};
  gload(0);
  for (int kt = 0; kt < NT; ++kt) {
    *(s16x8*)&As[srow * 32 + scol] = cvt8(ra);
    *(s16x8*)&Bs[srow * 32 + scol] = cvt8(rb);
    __syncthreads();
    if (kt + 1 < NT) gload(kt + 1);  // prefetch overlaps frag reads + MFMA
    bf16x8 a0 = *(const bf16x8*)&As[(wm + l16) * 32 + quad * 8];
    bf16x8 a1 = *(const bf16x8*)&As[(wm + 16 + l16) * 32 + quad * 8];
    bf16x8 b0 = *(const bf16x8*)&Bs[(wn + l16) * 32 + quad * 8];
    bf16x8 b1 = *(const bf16x8*)&Bs[(wn + 16 + l16) * 32 + quad * 8];
    acc[0][0] = MFMA16(a0, b0, acc[0][0], 0, 0, 0);
    acc[0][1] = MFMA16(a0, b1, acc[0][1], 0, 0, 0);
    acc[1][0] = MFMA16(a1, b0, acc[1][0], 0, 0, 0);
    acc[1][1] = MFMA16(a1, b1, acc[1][1], 0, 0, 0);
    __syncthreads();
  }
  #pragma unroll
  for (int i = 0; i < 2; ++i)
    #pragma unroll
    for (int j = 0; j < 2; ++j) {
      int col = n0 + wn + j * 16 + l16;
      #pragma unroll
      for (int r = 0; r < 4; ++r) {
        int row = m0 + wm + i * 16 + quad * 4 + r;
        C[(long)row * ldc + col] = f2bf(acc[i][j][r]);
      }
    }
}

// ---- bf16-input 64x64 GEMM (R2-proven): global_load_lds PD=4 ring, vmcnt pipeline ----
// EPI 1 (Weff): v += e0[row*1536+col] (f32 Wo1), store bf16.
// EPI 2 (out):  v += e0[col] + e1[row]*e2[col], store f32.
template <int EPI>
__device__ void bgemm64(const short* __restrict__ A, int lda,
                        const short* __restrict__ B, int ldb,
                        void* __restrict__ C, int ldc, int NT, int m0, int n0,
                        const float* __restrict__ e0, const float* __restrict__ e1,
                        const float* __restrict__ e2, short* lds) {
  short* As = lds;               // 4 bufs * 2048 shorts
  short* Bs = lds + 4 * 2048;
  const int tid = threadIdx.x;
  const int wave = tid >> 6, lane = tid & 63;
  const int quad = lane >> 4, l16 = lane & 15;
  const int wm = (wave & 1) * 32, wn = (wave >> 1) * 32;
  const int srow = tid >> 2, scol = (tid & 3) * 8;
  const short* Ag = A + (long)(m0 + srow) * lda + scol;
  const short* Bg = B + (long)(n0 + srow) * ldb + scol;
  const int ldsoff = wave * 512;  // wave-uniform base (16 rows/wave)
  auto issue = [&](int kt) {
    int buf = kt & 3; int ko = kt * 32;
    __builtin_amdgcn_global_load_lds((gas_t)(Ag + ko), (las_t)(As + buf * 2048 + ldsoff), 16, 0, 0);
    __builtin_amdgcn_global_load_lds((gas_t)(Bg + ko), (las_t)(Bs + buf * 2048 + ldsoff), 16, 0, 0);
  };
  f32x4 acc[2][2] = {};
  issue(0); issue(1); issue(2);
  for (int kt = 0; kt < NT; ++kt) {
    if (kt + 3 < NT) issue(kt + 3);
    int ahead = NT - 1 - kt; if (ahead > 3) ahead = 3;
    if (ahead == 3)      asm volatile("s_waitcnt vmcnt(6)" ::: "memory");
    else if (ahead == 2) asm volatile("s_waitcnt vmcnt(4)" ::: "memory");
    else if (ahead == 1) asm volatile("s_waitcnt vmcnt(2)" ::: "memory");
    else                 asm volatile("s_waitcnt vmcnt(0)" ::: "memory");
    asm volatile("s_barrier" ::: "memory");
    const short* as = As + (kt & 3) * 2048;
    const short* bs = Bs + (kt & 3) * 2048;
    bf16x8 a0 = *(const bf16x8*)&as[(wm + l16) * 32 + quad * 8];
    bf16x8 a1 = *(const bf16x8*)&as[(wm + 16 + l16) * 32 + quad * 8];
    bf16x8 b0 = *(const bf16x8*)&bs[(wn + l16) * 32 + quad * 8];
    bf16x8 b1 = *(const bf16x8*)&bs[(wn + 16 + l16) * 32 + quad * 8];
    acc[0][0] = MFMA16(a0, b0, acc[0][0], 0, 0, 0);
    acc[0][1] = MFMA16(a0, b1, acc[0][1], 0, 0, 0);
    acc[1][0] = MFMA16(a1, b0, acc[1][0], 0, 0, 0);
    acc[1][1] = MFMA16(a1, b1, acc[1][1], 0, 0, 0);
    asm volatile("s_barrier" ::: "memory");
  }
  #pragma unroll
  for (int i = 0; i < 2; ++i)
    #pragma unroll
    for (int j = 0; j < 2; ++j) {
      int col = n0 + wn + j * 16 + l16;
      #pragma unroll
      for (int r = 0; r < 4; ++r) {
        int row = m0 + wm + i * 16 + quad * 4 + r;
        float v = acc[i][j][r];
        if constexpr (EPI == 1) {
          v += e0[(long)row * 1536 + col];
          ((short*)C)[(long)row * ldc + col] = f2bf(v);
        } else {
          v += e0[col] + e1[row] * e2[col];
          ((float*)C)[(long)row * ldc + col] = v;
        }
      }
    }
}

// ---- vu gate tile 32(M)x64(N), f32 staged: dual-B (Wv,Wu), gate+Wa -> wpart ----
__device__ void vu_tile(int mi, int ni, const float* __restrict__ X,
                        const float* __restrict__ Wv, const float* __restrict__ Wu,
                        const float* __restrict__ bv, const float* __restrict__ bu,
                        const float* __restrict__ Wa, float* __restrict__ wpart,
                        short* lds, float* red) {
  const int tid = threadIdx.x, wave = tid >> 6, lane = tid & 63;
  const int quad = lane >> 4, l16 = lane & 15;
  const int wm = (wave & 1) * 16, wn = (wave >> 1) * 32;
  const int m0 = mi * 32, n0 = ni * 64;
  const int srow = tid >> 2, scol = (tid & 3) * 8;
  short* As = lds;          // 32x32
  short* Bvs = lds + 1024;  // 64x32
  short* Bus = lds + 3072;  // 64x32
  const float* Ag  = X  + (long)(m0 + srow) * 1024 + scol;   // valid only tid<128
  const float* Bvg = Wv + (long)(n0 + srow) * 1024 + scol;
  const float* Bug = Wu + (long)(n0 + srow) * 1024 + scol;
  float ra[8], rv[8], ru[8];
  auto gload = [&](int kt) {
    long k = (long)kt * 32;
    if (tid < 128) {
      *(float4*)(ra)     = *(const float4*)(Ag + k);
      *(float4*)(ra + 4) = *(const float4*)(Ag + k + 4);
    }
    *(float4*)(rv)     = *(const float4*)(Bvg + k);
    *(float4*)(rv + 4) = *(const float4*)(Bvg + k + 4);
    *(float4*)(ru)     = *(const float4*)(Bug + k);
    *(float4*)(ru + 4) = *(const float4*)(Bug + k + 4);
  };
  f32x4 accv[2] = {}, accu[2] = {};
  gload(0);
  for (int kt = 0; kt < 32; ++kt) {
    if (tid < 128) *(s16x8*)&As[srow * 32 + scol] = cvt8(ra);
    *(s16x8*)&Bvs[srow * 32 + scol] = cvt8(rv);
    *(s16x8*)&Bus[srow * 32 + scol] = cvt8(ru);
    __syncthreads();
    if (kt + 1 < 32) gload(kt + 1);
    bf16x8 af = *(const bf16x8*)&As[(wm + l16) * 32 + quad * 8];
    bf16x8 v0 = *(const bf16x8*)&Bvs[(wn + l16) * 32 + quad * 8];
    bf16x8 v1 = *(const bf16x8*)&Bvs[(wn + 16 + l16) * 32 + quad * 8];
    bf16x8 u0 = *(const bf16x8*)&Bus[(wn + l16) * 32 + quad * 8];
    bf16x8 u1 = *(const bf16x8*)&Bus[(wn + 16 + l16) * 32 + quad * 8];
    accv[0] = MFMA16(af, v0, accv[0], 0, 0, 0);
    accv[1] = MFMA16(af, v1, accv[1], 0, 0, 0);
    accu[0] = MFMA16(af, u0, accu[0], 0, 0, 0);
    accu[1] = MFMA16(af, u1, accu[1], 0, 0, 0);
    __syncthreads();
  }
  float wsum[4] = {0.f, 0.f, 0.f, 0.f};
  #pragma unroll
  for (int j = 0; j < 2; ++j) {
    int col = n0 + wn + j * 16 + l16;
    float bvc = bv[col], buc = bu[col], wac = Wa[col];
    #pragma unroll
    for (int r = 0; r < 4; ++r) {
      float vv = tanhf(accv[j][r] + bvc);
      float uu = accu[j][r] + buc;
      wsum[r] += (vv / (1.0f + expf(-uu))) * wac;
    }
  }
  #pragma unroll
  for (int r = 0; r < 4; ++r) {
    float s = wsum[r];
    s += __shfl_down(s, 8, 16);
    s += __shfl_down(s, 4, 16);
    s += __shfl_down(s, 2, 16);
    s += __shfl_down(s, 1, 16);
    if (l16 == 0) red[(wave >> 1) * 32 + wm + quad * 4 + r] = s;
  }
  __syncthreads();
  if (tid < 32) wpart[ni * 2048 + m0 + tid] = red[tid] + red[32 + tid];
}

// ---- masked softmax over K=16 + pooling for one entity -> er (bf16), cf ----
__device__ void softmax_entity(int be, const float* __restrict__ ment,
    const int* __restrict__ ents, const int* __restrict__ msk,
    const float* __restrict__ wpart, const float* __restrict__ br,
    short* __restrict__ erb, float* __restrict__ cf,
    float* sm_a, int* sm_idx, float* sm_red) {
  const int b = be >> 7;  // E=128
  const int tid = threadIdx.x;
  __syncthreads();  // protect shared reuse across entities
  if (tid < 16) {
    int idx = ents[be * 16 + tid];
    sm_idx[tid] = idx;
    int j = (b << 8) + idx;
    float lw = wpart[j] + wpart[2048 + j] + wpart[4096 + j] + wpart[6144 + j];
    sm_a[tid] = msk[be * 16 + tid] ? lw : NEG_;
  }
  __syncthreads();
  if (tid == 0) {
    float mx = sm_a[0];
    #pragma unroll
    for (int k = 1; k < 16; ++k) mx = fmaxf(mx, sm_a[k]);
    float e[16], s = 0.f;
    #pragma unroll
    for (int k = 0; k < 16; ++k) { e[k] = expf(sm_a[k] - mx); s += e[k]; }
    float inv = 1.0f / s;
    #pragma unroll
    for (int k = 0; k < 16; ++k) sm_a[k] = e[k] * inv;
  }
  __syncthreads();
  const float* Xr = ment + ((long)b << 18);
  const int h0 = tid * 4;
  float ax = 0.f, ay = 0.f, az = 0.f, aw = 0.f;
  #pragma unroll
  for (int k = 0; k < 16; ++k) {
    float ak = sm_a[k];
    float4 xv = *(const float4*)&Xr[(long)sm_idx[k] * 1024 + h0];
    ax += ak * xv.x; ay += ak * xv.y; az += ak * xv.z; aw += ak * xv.w;
  }
  short* er = erb + (long)be * 1024 + h0;
  er[0] = f2bf(ax); er[1] = f2bf(ay); er[2] = f2bf(az); er[3] = f2bf(aw);
  float4 brv = *(const float4*)&br[h0];
  float c = ax * brv.x + ay * brv.y + az * brv.z + aw * brv.w;
  #pragma unroll
  for (int off = 32; off > 0; off >>= 1) c += __shfl_down(c, off);
  if ((tid & 63) == 0) sm_red[tid >> 6] = c;
  __syncthreads();
  if (tid == 0) cf[be] = sm_red[0] + sm_red[1] + sm_red[2] + sm_red[3];
}

// ================= kernels =================
// L1: s_wT = Wr @ rm^T (256) | U = Wo2 @ rm^T (256) | vu gate (256)
__global__ __launch_bounds__(256) void k1(
    const float* __restrict__ rm, const float* __restrict__ ment,
    const float* __restrict__ Wv, const float* __restrict__ Wu,
    const float* __restrict__ bv, const float* __restrict__ bu,
    const float* __restrict__ Wa, const float* __restrict__ Wr,
    const float* __restrict__ Wo, short* __restrict__ swTb,
    short* __restrict__ Ub, float* __restrict__ wpart) {
  __shared__ short lds[5120];
  __shared__ float red[64];
  const int blk = blockIdx.x;
  if (blk < 256) {
    fgemm64<16>(Wr, 512, rm, 512, swTb, 1024, (blk >> 4) * 64, (blk & 15) * 64, lds);
  } else if (blk < 512) {
    int q = blk - 256;
    fgemm64<16>(Wo + 1024, 1536, rm, 512, Ub, 1024, (q >> 4) * 64, (q & 15) * 64, lds);
  } else {
    int q = blk - 512;                 // ni-outer: same-X blocks spread rows
    vu_tile(q & 63, q >> 6, ment, Wv, Wu, bv, bu, Wa, wpart, lds, red);
  }
}

// L2: Weff = Wo1 + U @ s_wT^T (256) | gw2 = rowsum(U) (4) | softmax (256)
__global__ __launch_bounds__(256) void k2(
    const short* __restrict__ Ub, const short* __restrict__ swTb,
    const float* __restrict__ Wo, const float* __restrict__ ment,
    const int* __restrict__ ents, const int* __restrict__ msk,
    const float* __restrict__ wpart, const float* __restrict__ br,
    short* __restrict__ Weffb, float* __restrict__ gw2,
    short* __restrict__ erb, float* __restrict__ cf) {
  __shared__ short lds[16384];
  __shared__ float sm_a[16];
  __shared__ int   sm_idx[16];
  __shared__ float sm_red[4];
  const int blk = blockIdx.x, tid = threadIdx.x;
  if (blk < 256) {
    bgemm64<1>(Ub, 1024, swTb, 1024, Weffb, 1024, 32,
               (blk >> 4) * 64, (blk & 15) * 64, Wo, nullptr, nullptr, lds);
  } else if (blk < 260) {
    int row = (blk - 256) * 256 + tid;
    const short* u = Ub + (long)row * 1024;
    float s = 0.f;
    for (int k = 0; k < 1024; k += 8) {
      s16x8 v = *(const s16x8*)&u[k];
      union { s16x8 s; bf16x8 b; } w; w.s = v;
      #pragma unroll
      for (int j = 0; j < 8; ++j) s += (float)w.b[j];
    }
    gw2[row] = s;
  } else {
    int s4 = (blk - 260) * 4;
    for (int e = 0; e < 4; ++e)
      softmax_entity(s4 + e, ment, ents, msk, wpart, br, erb, cf,
                     sm_a, sm_idx, sm_red);
  }
}

// L3: out = er @ Weff^T + bo + cf*gw2 (256)
__global__ __launch_bounds__(256) void k3(
    const short* __restrict__ erb, const short* __restrict__ Weffb,
    const float* __restrict__ bo, const float* __restrict__ cf,
    const float* __restrict__ gw2, float* __restrict__ out) {
  __shared__ short lds[16384];
  const int blk = blockIdx.x;
  bgemm64<2>(erb, 1024, Weffb, 1024, out, 1024, 32,
             (blk >> 4) * 64, (blk & 15) * 64, bo, cf, gw2, lds);
}

extern "C" void kernel_launch(void* const* d_in, const int* in_sizes, int n_in,
                              void* d_out, int out_size, void* d_ws, size_t ws_size,
                              hipStream_t stream) {
  const float* ment = (const float*)d_in[0];
  const int*   ents = (const int*)d_in[1];
  const int*   msk  = (const int*)d_in[2];
  const float* rm   = (const float*)d_in[3];
  const float* Wv   = (const float*)d_in[4];
  const float* bv   = (const float*)d_in[5];
  const float* Wu   = (const float*)d_in[6];
  const float* bu   = (const float*)d_in[7];
  const float* Wa   = (const float*)d_in[8];
  // d_in[9] = ba: drops out (softmax shift-invariance)
  const float* Wr   = (const float*)d_in[10];
  const float* br   = (const float*)d_in[11];
  const float* Wo   = (const float*)d_in[12];
  const float* bo   = (const float*)d_in[13];
  float* out = (float*)d_out;

  char* p = (char*)d_ws;
  auto alloc = [&](size_t bytes) {
    void* q = (void*)p; p += (bytes + 255) & ~(size_t)255; return q;
  };
  short* swTb  = (short*)alloc((size_t)1024 * 1024 * 2);  // s_wT[j,r] bf16
  short* Ub    = (short*)alloc((size_t)1024 * 1024 * 2);  // U[h,r] bf16
  short* Weffb = (short*)alloc((size_t)1024 * 1024 * 2);  // Wo1 + U@s_wT^T bf16
  short* erb   = (short*)alloc((size_t)1024 * 1024 * 2);  // entity reprs bf16
  float* wpart = (float*)alloc((size_t)4 * 2048 * 4);     // gate partials
  float* cf    = (float*)alloc((size_t)1024 * 4);         // er . br
  float* gw2   = (float*)alloc((size_t)1024 * 4);         // rowsum(U)

  k1<<<768, 256, 0, stream>>>(rm, ment, Wv, Wu, bv, bu, Wa, Wr, Wo,
                              swTb, Ub, wpart);
  k2<<<516, 256, 0, stream>>>(Ub, swTb, Wo, ment, ents, msk, wpart, br,
                              Weffb, gw2, erb, cf);
  k3<<<256, 256, 0, stream>>>(erb, Weffb, bo, cf, gw2, out);
}